// Round 4
// baseline (158.482 us; speedup 1.0000x reference)
//
#include <hip/hip_runtime.h>

#define DIM 512
#define NROWS 65536
#define NBLOCKS 4096   // 4 waves/block * 4 rows/wave * 4096 = 65536 rows

// Fused single kernel: distance + per-block candidate store + "last block
// finishes" final reduce + winning-row copy. Avoids the second dispatch.
//
// d_ws layout: [0..3] u32 completion counter; [128..] u64 cand[NBLOCKS].
__global__ __launch_bounds__(256) void nn_fused_kernel(
    const float* __restrict__ x,
    const float* __restrict__ ctx,
    unsigned int* __restrict__ count,
    unsigned long long* __restrict__ cand,
    float* __restrict__ out) {
  const int lane = threadIdx.x & 63;
  const int wave_in_block = threadIdx.x >> 6;
  const int base = (((blockIdx.x << 2) | wave_in_block) << 2);  // 4 rows/wave

  // --- distance phase: one-shot, 8 dwordx4 loads in flight per lane ---
  const float* r = ctx + (size_t)base * DIM + lane * 4;
  float4 ca[4], cb[4];
#pragma unroll
  for (int j = 0; j < 4; ++j) {
    ca[j] = *reinterpret_cast<const float4*>(r + j * DIM);
    cb[j] = *reinterpret_cast<const float4*>(r + j * DIM + 256);
  }
  const float4 xa = *reinterpret_cast<const float4*>(x + lane * 4);
  const float4 xb = *reinterpret_cast<const float4*>(x + 256 + lane * 4);

  float s[4];
#pragma unroll
  for (int j = 0; j < 4; ++j) {
    float t = 0.f, d;
    d = ca[j].x - xa.x; t = fmaf(d, d, t);
    d = ca[j].y - xa.y; t = fmaf(d, d, t);
    d = ca[j].z - xa.z; t = fmaf(d, d, t);
    d = ca[j].w - xa.w; t = fmaf(d, d, t);
    d = cb[j].x - xb.x; t = fmaf(d, d, t);
    d = cb[j].y - xb.y; t = fmaf(d, d, t);
    d = cb[j].z - xb.z; t = fmaf(d, d, t);
    d = cb[j].w - xb.w; t = fmaf(d, d, t);
    s[j] = t;
  }
#pragma unroll
  for (int off = 32; off; off >>= 1) {
#pragma unroll
    for (int j = 0; j < 4; ++j) s[j] += __shfl_xor(s[j], off, 64);
  }

  float best_d = s[0];
  int best_i = base;
#pragma unroll
  for (int j = 1; j < 4; ++j) {
    if (s[j] < best_d) { best_d = s[j]; best_i = base + j; }  // strict < => first idx wins
  }

  // --- block reduce -> candidate store -> completion count ---
  __shared__ unsigned long long lds[4];
  __shared__ int s_last;
  if (lane == 0) {
    // dist >= 0 -> IEEE bits order-preserving; idx in low bits => first-idx tie-break.
    lds[wave_in_block] =
        ((unsigned long long)__float_as_uint(best_d) << 32) | (unsigned)best_i;
  }
  __syncthreads();
  if (threadIdx.x == 0) {
    unsigned long long m = lds[0];
#pragma unroll
    for (int j = 1; j < 4; ++j) m = lds[j] < m ? lds[j] : m;
    cand[blockIdx.x] = m;
    __threadfence();  // agent-scope: make cand visible before counter bump
    unsigned int prev = atomicAdd(count, 1u);  // device-scope by default
    s_last = (prev == NBLOCKS - 1);
  }
  __syncthreads();
  if (!s_last) return;

  // --- last block: final reduce over 4096 candidates + row copy ---
  __threadfence();  // acquire side: invalidate stale cache lines
  const int t = threadIdx.x;
  unsigned long long m = ~0ull;
#pragma unroll
  for (int k = 0; k < NBLOCKS / 256; ++k) {
    unsigned long long v = cand[t + (k << 8)];
    m = v < m ? v : m;
  }
#pragma unroll
  for (int off = 32; off; off >>= 1) {
    unsigned long long o = __shfl_xor(m, off, 64);
    m = o < m ? o : m;
  }
  __shared__ unsigned long long lds2[4];
  __shared__ int s_idx;
  if ((t & 63) == 0) lds2[t >> 6] = m;
  __syncthreads();
  if (t == 0) {
    unsigned long long mm = lds2[0];
#pragma unroll
    for (int j = 1; j < 4; ++j) mm = lds2[j] < mm ? lds2[j] : mm;
    s_idx = (int)(unsigned)(mm & 0xFFFFFFFFull);
  }
  __syncthreads();

  const float* src = ctx + (size_t)s_idx * DIM;
  reinterpret_cast<float2*>(out)[t] = reinterpret_cast<const float2*>(src)[t];
}

extern "C" void kernel_launch(void* const* d_in, const int* in_sizes, int n_in,
                              void* d_out, int out_size, void* d_ws, size_t ws_size,
                              hipStream_t stream) {
  const float* x = (const float*)d_in[0];
  const float* ctx = (const float*)d_in[1];
  float* out = (float*)d_out;
  unsigned int* count = (unsigned int*)d_ws;
  unsigned long long* cand = (unsigned long long*)((char*)d_ws + 128);

  // Reset completion counter every call (graph-capture safe, deterministic).
  hipMemsetAsync(d_ws, 0, 4, stream);
  nn_fused_kernel<<<NBLOCKS, 256, 0, stream>>>(x, ctx, count, cand, out);
}

// Round 5
// 27.506 us; speedup vs baseline: 5.7618x; 5.7618x over previous
//
#include <hip/hip_runtime.h>

#define DIM 512
#define NROWS 65536
#define NBLOCKS 2048   // 4 waves/block -> 8192 waves; 4 rows/wave/iter -> 2 iters

// One wave computes 4 rows per iteration. Lane l covers floats [l*4, l*4+4)
// and [256 + l*4, ...) of each row: fully coalesced dwordx4, 8 loads in
// flight per wave per iteration (8 KiB). No global atomics: per-block best
// goes to d_ws via a plain store. (Fused single-kernel variant with
// threadfence+counter measured 6x WORSE — cross-XCD fence cost; keep 2 kernels.)
__global__ __launch_bounds__(256) void nn_dist_kernel(
    const float* __restrict__ x,
    const float* __restrict__ ctx,
    unsigned long long* __restrict__ block_best) {
  const int lane = threadIdx.x & 63;
  const int wave_in_block = threadIdx.x >> 6;
  const int wave_global = (blockIdx.x << 2) | wave_in_block;
  const int n_waves = NBLOCKS << 2;  // 8192

  const float4 xa = *reinterpret_cast<const float4*>(x + lane * 4);
  const float4 xb = *reinterpret_cast<const float4*>(x + 256 + lane * 4);

  float best_d = 3.402823466e38f;
  int best_i = 0;

  for (int base = wave_global * 4; base < NROWS; base += n_waves * 4) {
    const float* r = ctx + (size_t)base * DIM + lane * 4;
    float4 ca[4], cb[4];
#pragma unroll
    for (int j = 0; j < 4; ++j) {
      ca[j] = *reinterpret_cast<const float4*>(r + j * DIM);
      cb[j] = *reinterpret_cast<const float4*>(r + j * DIM + 256);
    }
    float s[4];
#pragma unroll
    for (int j = 0; j < 4; ++j) {
      float t = 0.f, d;
      d = ca[j].x - xa.x; t = fmaf(d, d, t);
      d = ca[j].y - xa.y; t = fmaf(d, d, t);
      d = ca[j].z - xa.z; t = fmaf(d, d, t);
      d = ca[j].w - xa.w; t = fmaf(d, d, t);
      d = cb[j].x - xb.x; t = fmaf(d, d, t);
      d = cb[j].y - xb.y; t = fmaf(d, d, t);
      d = cb[j].z - xb.z; t = fmaf(d, d, t);
      d = cb[j].w - xb.w; t = fmaf(d, d, t);
      s[j] = t;
    }
    // 4 independent wave-wide sums; the 6-step chains pipeline.
#pragma unroll
    for (int off = 32; off; off >>= 1) {
#pragma unroll
      for (int j = 0; j < 4; ++j) s[j] += __shfl_xor(s[j], off, 64);
    }
#pragma unroll
    for (int j = 0; j < 4; ++j) {
      if (s[j] < best_d) { best_d = s[j]; best_i = base + j; }  // strict < => first idx wins
    }
  }

  // Block-level reduce: 4 waves -> 1 plain store. dist >= 0 so IEEE bits are
  // order-preserving; idx in low bits => smallest idx wins exact ties.
  __shared__ unsigned long long lds[4];
  if (lane == 0) {
    lds[wave_in_block] =
        ((unsigned long long)__float_as_uint(best_d) << 32) | (unsigned)best_i;
  }
  __syncthreads();
  if (threadIdx.x == 0) {
    unsigned long long m = lds[0];
#pragma unroll
    for (int j = 1; j < 4; ++j) m = lds[j] < m ? lds[j] : m;
    block_best[blockIdx.x] = m;
  }
}

// Single block: reduce 2048 candidates, then copy the winning row.
__global__ __launch_bounds__(256) void nn_reduce_copy_kernel(
    const float* __restrict__ ctx,
    const unsigned long long* __restrict__ block_best,
    float* __restrict__ out) {
  __shared__ unsigned long long lds[4];
  __shared__ int s_idx;
  const int t = threadIdx.x;

  unsigned long long m = ~0ull;
#pragma unroll
  for (int k = 0; k < NBLOCKS / 256; ++k) {
    unsigned long long v = block_best[t + (k << 8)];
    m = v < m ? v : m;
  }
#pragma unroll
  for (int off = 32; off; off >>= 1) {
    unsigned long long o = __shfl_xor(m, off, 64);
    m = o < m ? o : m;
  }
  if ((t & 63) == 0) lds[t >> 6] = m;
  __syncthreads();
  if (t == 0) {
    unsigned long long mm = lds[0];
#pragma unroll
    for (int j = 1; j < 4; ++j) mm = lds[j] < mm ? lds[j] : mm;
    s_idx = (int)(unsigned)(mm & 0xFFFFFFFFull);
  }
  __syncthreads();

  const float* src = ctx + (size_t)s_idx * DIM;
  reinterpret_cast<float2*>(out)[t] = reinterpret_cast<const float2*>(src)[t];
}

extern "C" void kernel_launch(void* const* d_in, const int* in_sizes, int n_in,
                              void* d_out, int out_size, void* d_ws, size_t ws_size,
                              hipStream_t stream) {
  const float* x = (const float*)d_in[0];
  const float* ctx = (const float*)d_in[1];
  float* out = (float*)d_out;
  unsigned long long* block_best = (unsigned long long*)d_ws;  // 2048 * 8 B = 16 KiB

  nn_dist_kernel<<<NBLOCKS, 256, 0, stream>>>(x, ctx, block_best);
  nn_reduce_copy_kernel<<<1, 256, 0, stream>>>(ctx, block_best, out);
}